// Round 6
// baseline (98.395 us; speedup 1.0000x reference)
//
#include <hip/hip_runtime.h>
#include <hip/hip_bf16.h>

#define BATCH 2
#define CH 256
#define HW 4096
#define HEADS 8
#define HDIM 32
#define GROUPS 32
#define EPS 1e-5f
#define SCALE 0.17677669529663687f  // 32^-0.5
#define QSCALE (0.17677669529663687f * 1.4426950408889634f)  // scale * log2(e)

typedef short s16x8 __attribute__((ext_vector_type(8)));
typedef float floatx4 __attribute__((ext_vector_type(4)));
typedef unsigned short ushort_t;
typedef unsigned int uint_t;

static __device__ __forceinline__ ushort_t f2bf(float f) {
    __hip_bfloat16 h = __float2bfloat16(f);
    return *reinterpret_cast<ushort_t*>(&h);
}

// pack two f32 -> one u32 of 2 bf16 (truncation) via single v_perm_b32
static __device__ __forceinline__ uint_t pk2(float lo, float hi) {
    return __builtin_amdgcn_perm(__float_as_uint(hi), __float_as_uint(lo), 0x07060302u);
}

static __device__ __forceinline__ void gload_lds16(const ushort_t* g, ushort_t* l) {
    __builtin_amdgcn_global_load_lds((const __attribute__((address_space(1))) void*)g,
                                     (__attribute__((address_space(3))) void*)l, 16, 0, 0);
}

// ---------------- Kernel 0: convert weights to bf16 once ----------------
__global__ void wcvt(const float* __restrict__ wq, const float* __restrict__ wo,
                     ushort_t* __restrict__ dst) {
    int i = blockIdx.x * 256 + threadIdx.x;  // 65536 threads, 4 floats each
    float4 v = (i < 49152) ? ((const float4*)wq)[i] : ((const float4*)wo)[i - 49152];
    ushort_t p[4] = {f2bf(v.x), f2bf(v.y), f2bf(v.z), f2bf(v.w)};
    uint2 o;
    o.x = (uint_t)p[0] | ((uint_t)p[1] << 16);
    o.y = (uint_t)p[2] | ((uint_t)p[3] << 16);
    *(uint2*)&dst[(size_t)i * 4] = o;
}

// ---------------- Kernel 1: groupnorm stats ----------------
__global__ void gn_stats(const float* __restrict__ x, float* __restrict__ stats) {
    int bg = blockIdx.x;
    const float4* xv = (const float4*)(x + (size_t)bg * 8 * HW);
    int t = threadIdx.x;
    float s = 0.f, ss = 0.f;
    for (int i = t; i < 8192; i += 256) {
        float4 v = xv[i];
        s  += v.x + v.y + v.z + v.w;
        ss += v.x*v.x + v.y*v.y + v.z*v.z + v.w*v.w;
    }
    #pragma unroll
    for (int off = 32; off; off >>= 1) {
        s  += __shfl_down(s, off);
        ss += __shfl_down(ss, off);
    }
    __shared__ float rs[4], rss[4];
    int wave = t >> 6;
    if ((t & 63) == 0) { rs[wave] = s; rss[wave] = ss; }
    __syncthreads();
    if (t == 0) {
        s  = rs[0] + rs[1] + rs[2] + rs[3];
        ss = rss[0] + rss[1] + rss[2] + rss[3];
        float mu  = s / 32768.f;
        float var = ss / 32768.f - mu * mu;
        stats[bg * 2]     = mu;
        stats[bg * 2 + 1] = rsqrtf(var + EPS);
    }
}

// ---------------- Kernel 2: normalize + transpose to [b][n][c] bf16 ----------------
__global__ void norm_transpose(const float* __restrict__ x, const float* __restrict__ stats,
                               const float* __restrict__ gw, const float* __restrict__ gb,
                               ushort_t* __restrict__ xn) {
    __shared__ ushort_t tile[64][40];
    int b = blockIdx.z, c0 = blockIdx.y * 32, n0 = blockIdx.x * 64;
    int t = threadIdx.x;
    #pragma unroll
    for (int i = 0; i < 8; i++) {
        int idx = i * 256 + t;
        int c = idx >> 6, n = idx & 63;
        int cc = c0 + c;
        float mu   = stats[(b * GROUPS + (cc >> 3)) * 2];
        float rstd = stats[(b * GROUPS + (cc >> 3)) * 2 + 1];
        float v = x[((size_t)b * CH + cc) * HW + n0 + n];
        v = (v - mu) * rstd * gw[cc] + gb[cc];
        tile[n][c] = f2bf(v);
    }
    __syncthreads();
    int n = t >> 2, chk = t & 3;
    uint4 val = *(const uint4*)&tile[n][chk * 8];
    *(uint4*)(xn + ((size_t)(b * HW + n0 + n)) * CH + c0 + chk * 8) = val;
}

// ---------------- Kernel 3: QKV gemm (bf16 weights) ----------------
__global__ void qkv_gemm(const ushort_t* __restrict__ xn, const ushort_t* __restrict__ wqb,
                         ushort_t* __restrict__ qo, ushort_t* __restrict__ ko,
                         ushort_t* __restrict__ vo) {
    __shared__ ushort_t Al[64][40];
    __shared__ ushort_t Bl[64][40];
    int b = blockIdx.z;
    int n0 = blockIdx.x * 64, o0 = blockIdx.y * 64;
    int t = threadIdx.x, lane = t & 63, wave = t >> 6;
    int lr = lane & 15, lk = lane >> 4;
    floatx4 acc[4] = {};
    for (int k0 = 0; k0 < 256; k0 += 32) {
        int row = t >> 2, chk = t & 3;
        *(uint4*)&Al[row][chk * 8] =
            *(const uint4*)(xn + ((size_t)(b * HW + n0 + row)) * CH + k0 + chk * 8);
        *(uint4*)&Bl[row][chk * 8] =
            *(const uint4*)(wqb + (size_t)(o0 + row) * CH + k0 + chk * 8);
        __syncthreads();
        s16x8 af = *(const s16x8*)&Al[wave * 16 + lr][lk * 8];
        #pragma unroll
        for (int ct = 0; ct < 4; ct++) {
            s16x8 bf = *(const s16x8*)&Bl[ct * 16 + lr][lk * 8];
            acc[ct] = __builtin_amdgcn_mfma_f32_16x16x32_bf16(af, bf, acc[ct], 0, 0, 0);
        }
        __syncthreads();
    }
    #pragma unroll
    for (int ct = 0; ct < 4; ct++) {
        int o = o0 + ct * 16 + lr;
        int sel = o >> 8;
        int h = (o >> 5) & 7;
        int d = o & 31;
        int nrow0 = n0 + wave * 16 + (lk << 2);
        if (sel == 0) {
            #pragma unroll
            for (int r = 0; r < 4; r++)
                qo[(((size_t)(b * HEADS + h)) * HW + nrow0 + r) * HDIM + d] =
                    f2bf(acc[ct][r] * QSCALE);
        } else if (sel == 1) {
            #pragma unroll
            for (int r = 0; r < 4; r++) {
                int tt = (nrow0 + r) & 63;
                int sg = 4 * ((tt >> 3) & 3) + 16 * ((((tt >> 2) & 1) << 1) | ((tt >> 5) & 1)) + (tt & 3);
                ko[(((size_t)(b * HEADS + h)) * HW + n0 + sg) * HDIM + d] = f2bf(acc[ct][r]);
            }
        } else {
            ushort_t pk[4];
            #pragma unroll
            for (int r = 0; r < 4; r++) pk[r] = f2bf(acc[ct][r]);
            *(uint2*)&vo[(((size_t)(b * HEADS + h)) * HDIM + d) * HW + nrow0] = *(uint2*)pk;
        }
    }
}

// ---------------- Kernel 4: flash attention v6 ----------------
// 8 waves / 512 threads per block; waves 0-3 process even k-tiles, 4-7 odd;
// partials merged at the end (valid since M==0). Double-buffer per parity.
__global__ void __launch_bounds__(512, 8)
attn6(const ushort_t* __restrict__ qg, const ushort_t* __restrict__ kg,
      const ushort_t* __restrict__ vg, ushort_t* __restrict__ og) {
    __shared__ ushort_t Kl[2][2][2048];  // [parity][dbuf][4KB tile]
    __shared__ ushort_t Vl[2][2][2048];
    const int bh = blockIdx.y;
    const int n0 = blockIdx.x * 64;
    const int t = threadIdx.x;
    const int lane = t & 63, w = t >> 6;   // 8 waves
    const int p = w >> 2;                  // wave parity: which k-tiles I compute
    const int qgp = w & 3;                 // q-group (16 rows)
    const int lr = lane & 15, lk = lane >> 4;

    const ushort_t* kb = kg + (size_t)bh * HW * HDIM;
    const ushort_t* vb = vg + (size_t)bh * HDIM * HW;

    // staging: half sh (threads sh*256..) stages parity-sh tiles
    const int tt = t & 255;
    const int sh = t >> 8;
    const int lrr = tt & 15, lkk = (tt >> 4) & 3, wv4 = tt >> 6;
    const ushort_t* gk = kb + ((size_t)(sh * 64) + (wv4 << 4) + lrr) * HDIM + lkk * 8;
    const ushort_t* gv = vb + (size_t)(((tt >> 7) << 4) + lrr) * HW + sh * 64 + ((tt >> 6) & 1) * 32 + lkk * 8;
    ushort_t* kd0 = &Kl[sh][0][wv4 << 9]; ushort_t* kd1 = &Kl[sh][1][wv4 << 9];
    ushort_t* vd0 = &Vl[sh][0][wv4 << 9]; ushort_t* vd1 = &Vl[sh][1][wv4 << 9];

    // compute-side buffers for my parity
    const ushort_t* Kb0 = &Kl[p][0][0]; const ushort_t* Kb1 = &Kl[p][1][0];
    const ushort_t* Vb0 = &Vl[p][0][0]; const ushort_t* Vb1 = &Vl[p][1][0];

    s16x8 qf = *(const s16x8*)(qg + ((size_t)bh * HW + n0 + qgp * 16 + lr) * HDIM + lk * 8);

    const s16x8 onesf = {0x3F80, 0x3F80, 0x3F80, 0x3F80, 0x3F80, 0x3F80, 0x3F80, 0x3F80};
    const floatx4 zf = {};
    floatx4 oacc[2] = {};
    floatx4 Lacc = {};

    auto stage = [&](ushort_t* kdn, ushort_t* vdn) {
        gload_lds16(gk, kdn);
        gload_lds16(gv, vdn);
        gk += 2 * 64 * HDIM;  // advance 2 tiles
        gv += 2 * 64;
    };
    auto compute = [&](const ushort_t* Kb, const ushort_t* Vb) {
        floatx4 sim[4];
        __builtin_amdgcn_s_setprio(1);
#pragma unroll
        for (int ct = 0; ct < 4; ct++) {
            s16x8 kf = *(const s16x8*)(Kb + ct * 512 + lane * 8);
            sim[ct] = __builtin_amdgcn_mfma_f32_16x16x32_bf16(kf, qf, zf, 0, 0, 0);
        }
        __builtin_amdgcn_s_setprio(0);
        s16x8 vf[4];
#pragma unroll
        for (int i = 0; i < 4; i++)
            vf[i] = *(const s16x8*)(Vb + i * 512 + lane * 8);
        float pp[4][4];
#pragma unroll
        for (int ct = 0; ct < 4; ct++)
#pragma unroll
            for (int r = 0; r < 4; r++) pp[ct][r] = __builtin_amdgcn_exp2f(sim[ct][r]);
        s16x8 pf[2];
#pragma unroll
        for (int s = 0; s < 2; s++) {
            union { uint_t u[4]; s16x8 v; } pu;
            pu.u[0] = pk2(pp[s][0], pp[s][1]);
            pu.u[1] = pk2(pp[s][2], pp[s][3]);
            pu.u[2] = pk2(pp[s + 2][0], pp[s + 2][1]);
            pu.u[3] = pk2(pp[s + 2][2], pp[s + 2][3]);
            pf[s] = pu.v;
        }
        __builtin_amdgcn_s_setprio(1);
#pragma unroll
        for (int s = 0; s < 2; s++) {
            oacc[0] = __builtin_amdgcn_mfma_f32_16x16x32_bf16(vf[s],     pf[s], oacc[0], 0, 0, 0);
            oacc[1] = __builtin_amdgcn_mfma_f32_16x16x32_bf16(vf[2 + s], pf[s], oacc[1], 0, 0, 0);
            Lacc    = __builtin_amdgcn_mfma_f32_16x16x32_bf16(onesf,     pf[s], Lacc,    0, 0, 0);
        }
        __builtin_amdgcn_s_setprio(0);
    };

#define WB { asm volatile("s_waitcnt vmcnt(0)" ::: "memory"); __syncthreads(); }

    // prologue: stage tiles 0,1 (each half its parity) into buf 0
    stage(kd0, vd0);
    WB
    // 32 supersteps, unrolled x2 (buffer index static)
    for (int s2 = 0; s2 < 16; s2++) {
        // even superstep: compute buf0, stage into buf1
        stage(kd1, vd1);
        compute(Kb0, Vb0);
        WB
        // odd superstep: compute buf1, stage into buf0 (except last)
        if (s2 < 15) {
            stage(kd0, vd0);
            compute(Kb1, Vb1);
            WB
        } else {
            compute(Kb1, Vb1);
            __syncthreads();
        }
    }
#undef WB

    // merge parity partials: waves 4-7 write (O, L) to scratch; waves 0-3 add.
    float* sc = (float*)&Kl[0][0][0];
    if (w >= 4) {
        float* dst = sc + ((size_t)((w - 4) * 64 + lane)) * 12;
        *(floatx4*)(dst)     = oacc[0];
        *(floatx4*)(dst + 4) = oacc[1];
        dst[8] = Lacc[0];
    }
    __syncthreads();
    if (w < 4) {
        const float* src = sc + ((size_t)(w * 64 + lane)) * 12;
        floatx4 o0 = *(const floatx4*)(src);
        floatx4 o1 = *(const floatx4*)(src + 4);
        float Lt = Lacc[0] + src[8];
        oacc[0] += o0;
        oacc[1] += o1;
        const int b = bh >> 3, h = bh & 7;
        float inv = 1.0f / Lt;
        int n = n0 + w * 16 + lr;
#pragma unroll
        for (int ct2 = 0; ct2 < 2; ct2++) {
            uint_t lo = (uint_t)f2bf(oacc[ct2][0] * inv) | ((uint_t)f2bf(oacc[ct2][1] * inv) << 16);
            uint_t hi = (uint_t)f2bf(oacc[ct2][2] * inv) | ((uint_t)f2bf(oacc[ct2][3] * inv) << 16);
            uint2 val = {lo, hi};
            *(uint2*)(og + ((size_t)b * HW + n) * CH + h * 32 + ct2 * 16 + lk * 4) = val;
        }
    }
}

// ---------------- Kernel 5: out projection + residual (bf16 weights) ----------------
__global__ void proj_res(const ushort_t* __restrict__ oa, const ushort_t* __restrict__ wob,
                         const float* __restrict__ x, float* __restrict__ out) {
    __shared__ ushort_t Al[64][40];
    __shared__ ushort_t Bl[64][40];
    int m0 = blockIdx.x * 64;
    int c0 = blockIdx.y * 64;
    int t = threadIdx.x, lane = t & 63, wave = t >> 6;
    int lr = lane & 15, lk = lane >> 4;
    floatx4 acc[4] = {};
    for (int k0 = 0; k0 < 256; k0 += 32) {
        int row = t >> 2, chk = t & 3;
        *(uint4*)&Al[row][chk * 8] =
            *(const uint4*)(oa + (size_t)(m0 + row) * CH + k0 + chk * 8);
        *(uint4*)&Bl[row][chk * 8] =
            *(const uint4*)(wob + (size_t)(c0 + row) * CH + k0 + chk * 8);
        __syncthreads();
        s16x8 af = *(const s16x8*)&Al[wave * 16 + lr][lk * 8];
        #pragma unroll
        for (int ct = 0; ct < 4; ct++) {
            s16x8 bf = *(const s16x8*)&Bl[ct * 16 + lr][lk * 8];
            acc[ct] = __builtin_amdgcn_mfma_f32_16x16x32_bf16(af, bf, acc[ct], 0, 0, 0);
        }
        __syncthreads();
    }
    int mrow0 = m0 + wave * 16 + (lk << 2);
    int b = mrow0 >> 12;
    int n = mrow0 & 4095;
    #pragma unroll
    for (int ct = 0; ct < 4; ct++) {
        int c = c0 + ct * 16 + lr;
        const float4 xv = *(const float4*)(x + ((size_t)(b * CH + c)) * HW + n);
        float4 ov;
        ov.x = acc[ct][0] + xv.x;
        ov.y = acc[ct][1] + xv.y;
        ov.z = acc[ct][2] + xv.z;
        ov.w = acc[ct][3] + xv.w;
        *(float4*)(out + ((size_t)(b * CH + c)) * HW + n) = ov;
    }
}

extern "C" void kernel_launch(void* const* d_in, const int* in_sizes, int n_in,
                              void* d_out, int out_size, void* d_ws, size_t ws_size,
                              hipStream_t stream) {
    const float* x    = (const float*)d_in[0];
    const float* gw   = (const float*)d_in[1];
    const float* gb   = (const float*)d_in[2];
    const float* wqkv = (const float*)d_in[3];
    const float* wout = (const float*)d_in[4];
    float* out = (float*)d_out;

    char* ws = (char*)d_ws;
    float* stats = (float*)ws;
    ushort_t* xn = (ushort_t*)(ws + 512);
    size_t per = (size_t)BATCH * HW * CH;
    ushort_t* q   = xn + per;
    ushort_t* k   = q + per;
    ushort_t* v   = k + per;
    ushort_t* oa  = v + per;
    ushort_t* wqb = oa + per;            // 196608 elements
    ushort_t* wob = wqb + 196608;        // 65536 elements

    wcvt<<<256, 256, 0, stream>>>(wqkv, wout, wqb);
    gn_stats<<<64, 256, 0, stream>>>(x, stats);
    norm_transpose<<<dim3(64, 8, 2), 256, 0, stream>>>(x, stats, gw, gb, xn);
    qkv_gemm<<<dim3(64, 12, 2), 256, 0, stream>>>(xn, wqb, q, k, v);
    attn6<<<dim3(64, 16), 512, 0, stream>>>(q, k, v, oa);
    proj_res<<<dim3(128, 4), 256, 0, stream>>>(oa, wob, x, out);
}

// Round 7
// 93.899 us; speedup vs baseline: 1.0479x; 1.0479x over previous
//
#include <hip/hip_runtime.h>
#include <hip/hip_bf16.h>

#define BATCH 2
#define CH 256
#define HW 4096
#define HEADS 8
#define HDIM 32
#define GROUPS 32
#define EPS 1e-5f
#define SCALE 0.17677669529663687f  // 32^-0.5
#define QSCALE (0.17677669529663687f * 1.4426950408889634f)  // scale * log2(e)

typedef short s16x8 __attribute__((ext_vector_type(8)));
typedef float floatx4 __attribute__((ext_vector_type(4)));
typedef unsigned short ushort_t;
typedef unsigned int uint_t;

static __device__ __forceinline__ ushort_t f2bf(float f) {
    __hip_bfloat16 h = __float2bfloat16(f);
    return *reinterpret_cast<ushort_t*>(&h);
}

// pack two f32 -> one u32 of 2 bf16 (truncation) via single v_perm_b32
static __device__ __forceinline__ uint_t pk2(float lo, float hi) {
    return __builtin_amdgcn_perm(__float_as_uint(hi), __float_as_uint(lo), 0x07060302u);
}

static __device__ __forceinline__ void gload_lds16(const ushort_t* g, ushort_t* l) {
    __builtin_amdgcn_global_load_lds((const __attribute__((address_space(1))) void*)g,
                                     (__attribute__((address_space(3))) void*)l, 16, 0, 0);
}

// ---------------- Kernel 0: convert weights to bf16 once ----------------
__global__ void wcvt(const float* __restrict__ wq, const float* __restrict__ wo,
                     ushort_t* __restrict__ dst) {
    int i = blockIdx.x * 256 + threadIdx.x;  // 65536 threads, 4 floats each
    float4 v = (i < 49152) ? ((const float4*)wq)[i] : ((const float4*)wo)[i - 49152];
    ushort_t p[4] = {f2bf(v.x), f2bf(v.y), f2bf(v.z), f2bf(v.w)};
    uint2 o;
    o.x = (uint_t)p[0] | ((uint_t)p[1] << 16);
    o.y = (uint_t)p[2] | ((uint_t)p[3] << 16);
    *(uint2*)&dst[(size_t)i * 4] = o;
}

// ---------------- Kernel 1: groupnorm stats ----------------
__global__ void gn_stats(const float* __restrict__ x, float* __restrict__ stats) {
    int bg = blockIdx.x;
    const float4* xv = (const float4*)(x + (size_t)bg * 8 * HW);
    int t = threadIdx.x;
    float s = 0.f, ss = 0.f;
    for (int i = t; i < 8192; i += 256) {
        float4 v = xv[i];
        s  += v.x + v.y + v.z + v.w;
        ss += v.x*v.x + v.y*v.y + v.z*v.z + v.w*v.w;
    }
    #pragma unroll
    for (int off = 32; off; off >>= 1) {
        s  += __shfl_down(s, off);
        ss += __shfl_down(ss, off);
    }
    __shared__ float rs[4], rss[4];
    int wave = t >> 6;
    if ((t & 63) == 0) { rs[wave] = s; rss[wave] = ss; }
    __syncthreads();
    if (t == 0) {
        s  = rs[0] + rs[1] + rs[2] + rs[3];
        ss = rss[0] + rss[1] + rss[2] + rss[3];
        float mu  = s / 32768.f;
        float var = ss / 32768.f - mu * mu;
        stats[bg * 2]     = mu;
        stats[bg * 2 + 1] = rsqrtf(var + EPS);
    }
}

// ---------------- Kernel 2: normalize + transpose to [b][n][c] bf16 ----------------
__global__ void norm_transpose(const float* __restrict__ x, const float* __restrict__ stats,
                               const float* __restrict__ gw, const float* __restrict__ gb,
                               ushort_t* __restrict__ xn) {
    __shared__ ushort_t tile[64][40];
    int b = blockIdx.z, c0 = blockIdx.y * 32, n0 = blockIdx.x * 64;
    int t = threadIdx.x;
    #pragma unroll
    for (int i = 0; i < 8; i++) {
        int idx = i * 256 + t;
        int c = idx >> 6, n = idx & 63;
        int cc = c0 + c;
        float mu   = stats[(b * GROUPS + (cc >> 3)) * 2];
        float rstd = stats[(b * GROUPS + (cc >> 3)) * 2 + 1];
        float v = x[((size_t)b * CH + cc) * HW + n0 + n];
        v = (v - mu) * rstd * gw[cc] + gb[cc];
        tile[n][c] = f2bf(v);
    }
    __syncthreads();
    int n = t >> 2, chk = t & 3;
    uint4 val = *(const uint4*)&tile[n][chk * 8];
    *(uint4*)(xn + ((size_t)(b * HW + n0 + n)) * CH + c0 + chk * 8) = val;
}

// ---------------- Kernel 3: QKV gemm (bf16 weights) ----------------
__global__ void qkv_gemm(const ushort_t* __restrict__ xn, const ushort_t* __restrict__ wqb,
                         ushort_t* __restrict__ qo, ushort_t* __restrict__ ko,
                         ushort_t* __restrict__ vo) {
    __shared__ ushort_t Al[64][40];
    __shared__ ushort_t Bl[64][40];
    int b = blockIdx.z;
    int n0 = blockIdx.x * 64, o0 = blockIdx.y * 64;
    int t = threadIdx.x, lane = t & 63, wave = t >> 6;
    int lr = lane & 15, lk = lane >> 4;
    floatx4 acc[4] = {};
    for (int k0 = 0; k0 < 256; k0 += 32) {
        int row = t >> 2, chk = t & 3;
        *(uint4*)&Al[row][chk * 8] =
            *(const uint4*)(xn + ((size_t)(b * HW + n0 + row)) * CH + k0 + chk * 8);
        *(uint4*)&Bl[row][chk * 8] =
            *(const uint4*)(wqb + (size_t)(o0 + row) * CH + k0 + chk * 8);
        __syncthreads();
        s16x8 af = *(const s16x8*)&Al[wave * 16 + lr][lk * 8];
        #pragma unroll
        for (int ct = 0; ct < 4; ct++) {
            s16x8 bf = *(const s16x8*)&Bl[ct * 16 + lr][lk * 8];
            acc[ct] = __builtin_amdgcn_mfma_f32_16x16x32_bf16(af, bf, acc[ct], 0, 0, 0);
        }
        __syncthreads();
    }
    #pragma unroll
    for (int ct = 0; ct < 4; ct++) {
        int o = o0 + ct * 16 + lr;
        int sel = o >> 8;
        int h = (o >> 5) & 7;
        int d = o & 31;
        int nrow0 = n0 + wave * 16 + (lk << 2);
        if (sel == 0) {
            #pragma unroll
            for (int r = 0; r < 4; r++)
                qo[(((size_t)(b * HEADS + h)) * HW + nrow0 + r) * HDIM + d] =
                    f2bf(acc[ct][r] * QSCALE);
        } else if (sel == 1) {
            #pragma unroll
            for (int r = 0; r < 4; r++) {
                int tt = (nrow0 + r) & 63;
                int sg = 4 * ((tt >> 3) & 3) + 16 * ((((tt >> 2) & 1) << 1) | ((tt >> 5) & 1)) + (tt & 3);
                ko[(((size_t)(b * HEADS + h)) * HW + n0 + sg) * HDIM + d] = f2bf(acc[ct][r]);
            }
        } else {
            ushort_t pk[4];
            #pragma unroll
            for (int r = 0; r < 4; r++) pk[r] = f2bf(acc[ct][r]);
            *(uint2*)&vo[(((size_t)(b * HEADS + h)) * HDIM + d) * HW + nrow0] = *(uint2*)pk;
        }
    }
}

// ---------------- Kernel 4: flash attention v7 ----------------
// attn4 structure + quad-buffer + COUNTED vmcnt + RAW s_barrier (no drain):
// tile t+1/t+2 loads stay in flight across the barrier.
__global__ void __launch_bounds__(256, 4)
attn7(const ushort_t* __restrict__ qg, const ushort_t* __restrict__ kg,
      const ushort_t* __restrict__ vg, ushort_t* __restrict__ og) {
    __shared__ ushort_t Kl[4][2048];  // lane-ordered, 4KB/buf
    __shared__ ushort_t Vl[4][2048];
    const int bh = blockIdx.y;
    const int n0 = blockIdx.x * 64;
    const int t = threadIdx.x;
    const int lane = t & 63, w = t >> 6;
    const int lr = lane & 15, lk = lane >> 4;

    const ushort_t* kb = kg + (size_t)bh * HW * HDIM;
    const ushort_t* vb = vg + (size_t)bh * HDIM * HW;

    const int lrr = t & 15, lkk = (t >> 4) & 3, wv = t >> 6;
    const ushort_t* gk = kb + ((wv << 4) + lrr) * HDIM + lkk * 8;
    const ushort_t* gv = vb + (size_t)(((t >> 7) << 4) + lrr) * HW + ((t >> 6) & 1) * 32 + lkk * 8;
    ushort_t* kd0 = &Kl[0][wv << 9]; ushort_t* kd1 = &Kl[1][wv << 9];
    ushort_t* kd2 = &Kl[2][wv << 9]; ushort_t* kd3 = &Kl[3][wv << 9];
    ushort_t* vd0 = &Vl[0][wv << 9]; ushort_t* vd1 = &Vl[1][wv << 9];
    ushort_t* vd2 = &Vl[2][wv << 9]; ushort_t* vd3 = &Vl[3][wv << 9];

    // load Q and drain it BEFORE any staging so compiler waitcnt stays clean
    s16x8 qf = *(const s16x8*)(qg + ((size_t)bh * HW + n0 + w * 16 + lr) * HDIM + lk * 8);
    asm volatile("s_waitcnt vmcnt(0)" ::: "memory");

    const s16x8 onesf = {0x3F80, 0x3F80, 0x3F80, 0x3F80, 0x3F80, 0x3F80, 0x3F80, 0x3F80};
    const floatx4 zf = {};
    floatx4 oacc[2] = {};
    floatx4 Lacc = {};

    auto stage = [&](ushort_t* kdn, ushort_t* vdn) {
        gload_lds16(gk, kdn);
        gload_lds16(gv, vdn);
        gk += 64 * HDIM; gv += 64;
    };
    auto compute = [&](const ushort_t* Kb, const ushort_t* Vb) {
        floatx4 sim[4];
        __builtin_amdgcn_s_setprio(1);
#pragma unroll
        for (int ct = 0; ct < 4; ct++) {
            s16x8 kf = *(const s16x8*)(Kb + ct * 512 + lane * 8);
            sim[ct] = __builtin_amdgcn_mfma_f32_16x16x32_bf16(kf, qf, zf, 0, 0, 0);
        }
        __builtin_amdgcn_s_setprio(0);
        s16x8 vf[4];
#pragma unroll
        for (int i = 0; i < 4; i++)
            vf[i] = *(const s16x8*)(Vb + i * 512 + lane * 8);
        float p[4][4];
#pragma unroll
        for (int ct = 0; ct < 4; ct++)
#pragma unroll
            for (int r = 0; r < 4; r++) p[ct][r] = __builtin_amdgcn_exp2f(sim[ct][r]);
        s16x8 pf[2];
#pragma unroll
        for (int s = 0; s < 2; s++) {
            union { uint_t u[4]; s16x8 v; } pu;
            pu.u[0] = pk2(p[s][0], p[s][1]);
            pu.u[1] = pk2(p[s][2], p[s][3]);
            pu.u[2] = pk2(p[s + 2][0], p[s + 2][1]);
            pu.u[3] = pk2(p[s + 2][2], p[s + 2][3]);
            pf[s] = pu.v;
        }
        __builtin_amdgcn_s_setprio(1);
#pragma unroll
        for (int s = 0; s < 2; s++) {
            oacc[0] = __builtin_amdgcn_mfma_f32_16x16x32_bf16(vf[s],     pf[s], oacc[0], 0, 0, 0);
            oacc[1] = __builtin_amdgcn_mfma_f32_16x16x32_bf16(vf[2 + s], pf[s], oacc[1], 0, 0, 0);
            Lacc    = __builtin_amdgcn_mfma_f32_16x16x32_bf16(onesf,     pf[s], Lacc,    0, 0, 0);
        }
        __builtin_amdgcn_s_setprio(0);
    };

    // counted wait + RAW barrier: prefetched loads stay in flight
#define WN4 { asm volatile("s_waitcnt vmcnt(4)" ::: "memory"); __builtin_amdgcn_s_barrier(); }
#define WN2 { asm volatile("s_waitcnt vmcnt(2)" ::: "memory"); __builtin_amdgcn_s_barrier(); }
#define WN0 { asm volatile("s_waitcnt vmcnt(0)" ::: "memory"); __builtin_amdgcn_s_barrier(); }

    // prologue: stage tiles 0 and 1
    stage(kd0, vd0);
    stage(kd1, vd1);

    for (int it = 0; it < 15; it++) {
        stage(kd2, vd2); WN4 compute(Kl[0], Vl[0]);
        stage(kd3, vd3); WN4 compute(Kl[1], Vl[1]);
        stage(kd0, vd0); WN4 compute(Kl[2], Vl[2]);
        stage(kd1, vd1); WN4 compute(Kl[3], Vl[3]);
    }
    stage(kd2, vd2); WN4 compute(Kl[0], Vl[0]);  // t=60 (stages 62)
    stage(kd3, vd3); WN4 compute(Kl[1], Vl[1]);  // t=61 (stages 63)
    WN2 compute(Kl[2], Vl[2]);                   // t=62
    WN0 compute(Kl[3], Vl[3]);                   // t=63
#undef WN4
#undef WN2
#undef WN0

    const int b = bh >> 3, h = bh & 7;
    float inv = 1.0f / Lacc[0];
    int n = n0 + w * 16 + lr;
#pragma unroll
    for (int ct2 = 0; ct2 < 2; ct2++) {
        uint_t lo = (uint_t)f2bf(oacc[ct2][0] * inv) | ((uint_t)f2bf(oacc[ct2][1] * inv) << 16);
        uint_t hi = (uint_t)f2bf(oacc[ct2][2] * inv) | ((uint_t)f2bf(oacc[ct2][3] * inv) << 16);
        uint2 val = {lo, hi};
        *(uint2*)(og + ((size_t)b * HW + n) * CH + h * 32 + ct2 * 16 + lk * 4) = val;
    }
}

// ---------------- Kernel 5: out projection + residual (bf16 weights) ----------------
__global__ void proj_res(const ushort_t* __restrict__ oa, const ushort_t* __restrict__ wob,
                         const float* __restrict__ x, float* __restrict__ out) {
    __shared__ ushort_t Al[64][40];
    __shared__ ushort_t Bl[64][40];
    int m0 = blockIdx.x * 64;
    int c0 = blockIdx.y * 64;
    int t = threadIdx.x, lane = t & 63, wave = t >> 6;
    int lr = lane & 15, lk = lane >> 4;
    floatx4 acc[4] = {};
    for (int k0 = 0; k0 < 256; k0 += 32) {
        int row = t >> 2, chk = t & 3;
        *(uint4*)&Al[row][chk * 8] =
            *(const uint4*)(oa + (size_t)(m0 + row) * CH + k0 + chk * 8);
        *(uint4*)&Bl[row][chk * 8] =
            *(const uint4*)(wob + (size_t)(c0 + row) * CH + k0 + chk * 8);
        __syncthreads();
        s16x8 af = *(const s16x8*)&Al[wave * 16 + lr][lk * 8];
        #pragma unroll
        for (int ct = 0; ct < 4; ct++) {
            s16x8 bf = *(const s16x8*)&Bl[ct * 16 + lr][lk * 8];
            acc[ct] = __builtin_amdgcn_mfma_f32_16x16x32_bf16(af, bf, acc[ct], 0, 0, 0);
        }
        __syncthreads();
    }
    int mrow0 = m0 + wave * 16 + (lk << 2);
    int b = mrow0 >> 12;
    int n = mrow0 & 4095;
    #pragma unroll
    for (int ct = 0; ct < 4; ct++) {
        int c = c0 + ct * 16 + lr;
        const float4 xv = *(const float4*)(x + ((size_t)(b * CH + c)) * HW + n);
        float4 ov;
        ov.x = acc[ct][0] + xv.x;
        ov.y = acc[ct][1] + xv.y;
        ov.z = acc[ct][2] + xv.z;
        ov.w = acc[ct][3] + xv.w;
        *(float4*)(out + ((size_t)(b * CH + c)) * HW + n) = ov;
    }
}

extern "C" void kernel_launch(void* const* d_in, const int* in_sizes, int n_in,
                              void* d_out, int out_size, void* d_ws, size_t ws_size,
                              hipStream_t stream) {
    const float* x    = (const float*)d_in[0];
    const float* gw   = (const float*)d_in[1];
    const float* gb   = (const float*)d_in[2];
    const float* wqkv = (const float*)d_in[3];
    const float* wout = (const float*)d_in[4];
    float* out = (float*)d_out;

    char* ws = (char*)d_ws;
    float* stats = (float*)ws;
    ushort_t* xn = (ushort_t*)(ws + 512);
    size_t per = (size_t)BATCH * HW * CH;
    ushort_t* q   = xn + per;
    ushort_t* k   = q + per;
    ushort_t* v   = k + per;
    ushort_t* oa  = v + per;
    ushort_t* wqb = oa + per;            // 196608 elements
    ushort_t* wob = wqb + 196608;        // 65536 elements

    wcvt<<<256, 256, 0, stream>>>(wqkv, wout, wqb);
    gn_stats<<<64, 256, 0, stream>>>(x, stats);
    norm_transpose<<<dim3(64, 8, 2), 256, 0, stream>>>(x, stats, gw, gb, xn);
    qkv_gemm<<<dim3(64, 12, 2), 256, 0, stream>>>(xn, wqb, q, k, v);
    attn7<<<dim3(64, 16), 256, 0, stream>>>(q, k, v, oa);
    proj_res<<<dim3(128, 4), 256, 0, stream>>>(oa, wob, x, out);
}

// Round 8
// 88.276 us; speedup vs baseline: 1.1146x; 1.0637x over previous
//
#include <hip/hip_runtime.h>
#include <hip/hip_bf16.h>

#define BATCH 2
#define CH 256
#define HW 4096
#define HEADS 8
#define HDIM 32
#define GROUPS 32
#define EPS 1e-5f
#define SCALE 0.17677669529663687f  // 32^-0.5
#define QSCALE (0.17677669529663687f * 1.4426950408889634f)  // scale * log2(e)

typedef short s16x8 __attribute__((ext_vector_type(8)));
typedef float floatx4 __attribute__((ext_vector_type(4)));
typedef unsigned short ushort_t;
typedef unsigned int uint_t;

static __device__ __forceinline__ ushort_t f2bf(float f) {
    __hip_bfloat16 h = __float2bfloat16(f);
    return *reinterpret_cast<ushort_t*>(&h);
}

// pack two f32 -> one u32 of 2 bf16 (truncation) via single v_perm_b32
static __device__ __forceinline__ uint_t pk2(float lo, float hi) {
    return __builtin_amdgcn_perm(__float_as_uint(hi), __float_as_uint(lo), 0x07060302u);
}

static __device__ __forceinline__ void gload_lds16(const ushort_t* g, ushort_t* l) {
    __builtin_amdgcn_global_load_lds((const __attribute__((address_space(1))) void*)g,
                                     (__attribute__((address_space(3))) void*)l, 16, 0, 0);
}

// ---------------- Kernel 1: groupnorm stats + weight convert (fused launch) ----------------
__global__ void gn_stats_wcvt(const float* __restrict__ x, float* __restrict__ stats,
                              const float* __restrict__ wq, const float* __restrict__ wo,
                              ushort_t* __restrict__ wdst) {
    if (blockIdx.x >= 64) {
        int i = (blockIdx.x - 64) * 256 + threadIdx.x;  // 65536 lanes, 4 floats each
        float4 v = (i < 49152) ? ((const float4*)wq)[i] : ((const float4*)wo)[i - 49152];
        ushort_t p[4] = {f2bf(v.x), f2bf(v.y), f2bf(v.z), f2bf(v.w)};
        uint2 o;
        o.x = (uint_t)p[0] | ((uint_t)p[1] << 16);
        o.y = (uint_t)p[2] | ((uint_t)p[3] << 16);
        *(uint2*)&wdst[(size_t)i * 4] = o;
        return;
    }
    int bg = blockIdx.x;
    const float4* xv = (const float4*)(x + (size_t)bg * 8 * HW);
    int t = threadIdx.x;
    float s = 0.f, ss = 0.f;
    for (int i = t; i < 8192; i += 256) {
        float4 v = xv[i];
        s  += v.x + v.y + v.z + v.w;
        ss += v.x*v.x + v.y*v.y + v.z*v.z + v.w*v.w;
    }
    #pragma unroll
    for (int off = 32; off; off >>= 1) {
        s  += __shfl_down(s, off);
        ss += __shfl_down(ss, off);
    }
    __shared__ float rs[4], rss[4];
    int wave = t >> 6;
    if ((t & 63) == 0) { rs[wave] = s; rss[wave] = ss; }
    __syncthreads();
    if (t == 0) {
        s  = rs[0] + rs[1] + rs[2] + rs[3];
        ss = rss[0] + rss[1] + rss[2] + rss[3];
        float mu  = s / 32768.f;
        float var = ss / 32768.f - mu * mu;
        stats[bg * 2]     = mu;
        stats[bg * 2 + 1] = rsqrtf(var + EPS);
    }
}

// ---------------- Kernel 2: normalize + transpose to [b][n][c] bf16 ----------------
__global__ void norm_transpose(const float* __restrict__ x, const float* __restrict__ stats,
                               const float* __restrict__ gw, const float* __restrict__ gb,
                               ushort_t* __restrict__ xn) {
    __shared__ ushort_t tile[64][40];
    int b = blockIdx.z, c0 = blockIdx.y * 32, n0 = blockIdx.x * 64;
    int t = threadIdx.x;
    #pragma unroll
    for (int i = 0; i < 8; i++) {
        int idx = i * 256 + t;
        int c = idx >> 6, n = idx & 63;
        int cc = c0 + c;
        float mu   = stats[(b * GROUPS + (cc >> 3)) * 2];
        float rstd = stats[(b * GROUPS + (cc >> 3)) * 2 + 1];
        float v = x[((size_t)b * CH + cc) * HW + n0 + n];
        v = (v - mu) * rstd * gw[cc] + gb[cc];
        tile[n][c] = f2bf(v);
    }
    __syncthreads();
    int n = t >> 2, chk = t & 3;
    uint4 val = *(const uint4*)&tile[n][chk * 8];
    *(uint4*)(xn + ((size_t)(b * HW + n0 + n)) * CH + c0 + chk * 8) = val;
}

// ---------------- Kernel 3: QKV gemm (bf16 weights, reg-prefetch staging) ----------------
__global__ void qkv_gemm(const ushort_t* __restrict__ xn, const ushort_t* __restrict__ wqb,
                         ushort_t* __restrict__ qo, ushort_t* __restrict__ ko,
                         ushort_t* __restrict__ vo) {
    __shared__ ushort_t Al[64][40];
    __shared__ ushort_t Bl[64][40];
    int b = blockIdx.z;
    int n0 = blockIdx.x * 64, o0 = blockIdx.y * 64;
    int t = threadIdx.x, lane = t & 63, wave = t >> 6;
    int lr = lane & 15, lk = lane >> 4;
    int row = t >> 2, chk = t & 3;
    const ushort_t* asrc = xn + ((size_t)(b * HW + n0 + row)) * CH + chk * 8;
    const ushort_t* bsrc = wqb + (size_t)(o0 + row) * CH + chk * 8;
    floatx4 acc[4] = {};
    uint4 ra = *(const uint4*)(asrc);
    uint4 rb = *(const uint4*)(bsrc);
    for (int k0 = 0; k0 < 8; k0++) {
        *(uint4*)&Al[row][chk * 8] = ra;
        *(uint4*)&Bl[row][chk * 8] = rb;
        __syncthreads();
        if (k0 < 7) {  // prefetch next chunk; latency hides under MFMAs
            ra = *(const uint4*)(asrc + (k0 + 1) * 32);
            rb = *(const uint4*)(bsrc + (k0 + 1) * 32);
        }
        s16x8 af = *(const s16x8*)&Al[wave * 16 + lr][lk * 8];
        #pragma unroll
        for (int ct = 0; ct < 4; ct++) {
            s16x8 bf = *(const s16x8*)&Bl[ct * 16 + lr][lk * 8];
            acc[ct] = __builtin_amdgcn_mfma_f32_16x16x32_bf16(af, bf, acc[ct], 0, 0, 0);
        }
        __syncthreads();
    }
    #pragma unroll
    for (int ct = 0; ct < 4; ct++) {
        int o = o0 + ct * 16 + lr;
        int sel = o >> 8;
        int h = (o >> 5) & 7;
        int d = o & 31;
        int nrow0 = n0 + wave * 16 + (lk << 2);
        if (sel == 0) {
            #pragma unroll
            for (int r = 0; r < 4; r++)
                qo[(((size_t)(b * HEADS + h)) * HW + nrow0 + r) * HDIM + d] =
                    f2bf(acc[ct][r] * QSCALE);
        } else if (sel == 1) {
            #pragma unroll
            for (int r = 0; r < 4; r++) {
                int tt = (nrow0 + r) & 63;
                int sg = 4 * ((tt >> 3) & 3) + 16 * ((((tt >> 2) & 1) << 1) | ((tt >> 5) & 1)) + (tt & 3);
                ko[(((size_t)(b * HEADS + h)) * HW + n0 + sg) * HDIM + d] = f2bf(acc[ct][r]);
            }
        } else {
            ushort_t pk[4];
            #pragma unroll
            for (int r = 0; r < 4; r++) pk[r] = f2bf(acc[ct][r]);
            *(uint2*)&vo[(((size_t)(b * HEADS + h)) * HDIM + d) * HW + nrow0] = *(uint2*)pk;
        }
    }
}

// ---------------- Kernel 4: flash attention v8 ----------------
// KVBLK=128: two 64-key sub-tiles per barrier — halves the per-superstep
// drain+barrier cost vs v4. R4-proven sync (vmcnt0 + syncthreads). M == 0.
__global__ void __launch_bounds__(256, 4)
attn8(const ushort_t* __restrict__ qg, const ushort_t* __restrict__ kg,
      const ushort_t* __restrict__ vg, ushort_t* __restrict__ og) {
    __shared__ ushort_t Kl[2][2][2048];  // [dbuf][sub][4KB tile]
    __shared__ ushort_t Vl[2][2][2048];
    const int bh = blockIdx.y;
    const int n0 = blockIdx.x * 64;
    const int t = threadIdx.x;
    const int lane = t & 63, w = t >> 6;
    const int lr = lane & 15, lk = lane >> 4;

    const ushort_t* kb = kg + (size_t)bh * HW * HDIM;
    const ushort_t* vb = vg + (size_t)bh * HDIM * HW;

    const int lrr = t & 15, lkk = (t >> 4) & 3, wv = t >> 6;
    const ushort_t* gkX = kb + ((wv << 4) + lrr) * HDIM + lkk * 8;
    const ushort_t* gkY = gkX + 64 * HDIM;
    const ushort_t* gvX = vb + (size_t)(((t >> 7) << 4) + lrr) * HW + ((t >> 6) & 1) * 32 + lkk * 8;
    const ushort_t* gvY = gvX + 64;
    ushort_t* kdX[2] = {&Kl[0][0][wv << 9], &Kl[1][0][wv << 9]};
    ushort_t* kdY[2] = {&Kl[0][1][wv << 9], &Kl[1][1][wv << 9]};
    ushort_t* vdX[2] = {&Vl[0][0][wv << 9], &Vl[1][0][wv << 9]};
    ushort_t* vdY[2] = {&Vl[0][1][wv << 9], &Vl[1][1][wv << 9]};

    s16x8 qf = *(const s16x8*)(qg + ((size_t)bh * HW + n0 + w * 16 + lr) * HDIM + lk * 8);

    const s16x8 onesf = {0x3F80, 0x3F80, 0x3F80, 0x3F80, 0x3F80, 0x3F80, 0x3F80, 0x3F80};
    const floatx4 zf = {};
    floatx4 oacc[2] = {};
    floatx4 Lacc = {};

    auto stage0 = [&]() {
        gload_lds16(gkX, kdX[0]); gload_lds16(gkY, kdY[0]);
        gload_lds16(gvX, vdX[0]); gload_lds16(gvY, vdY[0]);
        gkX += 128 * HDIM; gkY += 128 * HDIM; gvX += 128; gvY += 128;
    };
    auto stage1 = [&]() {
        gload_lds16(gkX, kdX[1]); gload_lds16(gkY, kdY[1]);
        gload_lds16(gvX, vdX[1]); gload_lds16(gvY, vdY[1]);
        gkX += 128 * HDIM; gkY += 128 * HDIM; gvX += 128; gvY += 128;
    };
    auto computeSub = [&](const ushort_t* Kb, const ushort_t* Vb) {
        floatx4 sim[4];
        __builtin_amdgcn_s_setprio(1);
#pragma unroll
        for (int ct = 0; ct < 4; ct++) {
            s16x8 kf = *(const s16x8*)(Kb + ct * 512 + lane * 8);
            sim[ct] = __builtin_amdgcn_mfma_f32_16x16x32_bf16(kf, qf, zf, 0, 0, 0);
        }
        __builtin_amdgcn_s_setprio(0);
        s16x8 vf[4];
#pragma unroll
        for (int i = 0; i < 4; i++)
            vf[i] = *(const s16x8*)(Vb + i * 512 + lane * 8);
        s16x8 pf[2];
#pragma unroll
        for (int s = 0; s < 2; s++) {
            union { uint_t u[4]; s16x8 v; } pu;
            pu.u[0] = pk2(__builtin_amdgcn_exp2f(sim[s][0]),     __builtin_amdgcn_exp2f(sim[s][1]));
            pu.u[1] = pk2(__builtin_amdgcn_exp2f(sim[s][2]),     __builtin_amdgcn_exp2f(sim[s][3]));
            pu.u[2] = pk2(__builtin_amdgcn_exp2f(sim[s + 2][0]), __builtin_amdgcn_exp2f(sim[s + 2][1]));
            pu.u[3] = pk2(__builtin_amdgcn_exp2f(sim[s + 2][2]), __builtin_amdgcn_exp2f(sim[s + 2][3]));
            pf[s] = pu.v;
        }
        __builtin_amdgcn_s_setprio(1);
#pragma unroll
        for (int s = 0; s < 2; s++) {
            oacc[0] = __builtin_amdgcn_mfma_f32_16x16x32_bf16(vf[s],     pf[s], oacc[0], 0, 0, 0);
            oacc[1] = __builtin_amdgcn_mfma_f32_16x16x32_bf16(vf[2 + s], pf[s], oacc[1], 0, 0, 0);
            Lacc    = __builtin_amdgcn_mfma_f32_16x16x32_bf16(onesf,     pf[s], Lacc,    0, 0, 0);
        }
        __builtin_amdgcn_s_setprio(0);
    };

#define SYNCF { asm volatile("s_waitcnt vmcnt(0)" ::: "memory"); __syncthreads(); }

    stage0();          // superstep 0 -> buf0
    SYNCF
    for (int s2 = 0; s2 < 16; s2++) {
        stage1();      // odd superstep -> buf1
        computeSub(&Kl[0][0][0], &Vl[0][0][0]);
        computeSub(&Kl[0][1][0], &Vl[0][1][0]);
        SYNCF
        if (s2 < 15) {
            stage0();  // even superstep -> buf0
            computeSub(&Kl[1][0][0], &Vl[1][0][0]);
            computeSub(&Kl[1][1][0], &Vl[1][1][0]);
            SYNCF
        } else {
            computeSub(&Kl[1][0][0], &Vl[1][0][0]);
            computeSub(&Kl[1][1][0], &Vl[1][1][0]);
        }
    }
#undef SYNCF

    const int b = bh >> 3, h = bh & 7;
    float inv = 1.0f / Lacc[0];
    int n = n0 + w * 16 + lr;
#pragma unroll
    for (int ct2 = 0; ct2 < 2; ct2++) {
        uint_t lo = (uint_t)f2bf(oacc[ct2][0] * inv) | ((uint_t)f2bf(oacc[ct2][1] * inv) << 16);
        uint_t hi = (uint_t)f2bf(oacc[ct2][2] * inv) | ((uint_t)f2bf(oacc[ct2][3] * inv) << 16);
        uint2 val = {lo, hi};
        *(uint2*)(og + ((size_t)b * HW + n) * CH + h * 32 + ct2 * 16 + lk * 4) = val;
    }
}

// ---------------- Kernel 5: out projection + residual (bf16 weights, reg-prefetch) ----------------
__global__ void proj_res(const ushort_t* __restrict__ oa, const ushort_t* __restrict__ wob,
                         const float* __restrict__ x, float* __restrict__ out) {
    __shared__ ushort_t Al[64][40];
    __shared__ ushort_t Bl[64][40];
    int m0 = blockIdx.x * 64;
    int c0 = blockIdx.y * 64;
    int t = threadIdx.x, lane = t & 63, wave = t >> 6;
    int lr = lane & 15, lk = lane >> 4;
    int row = t >> 2, chk = t & 3;
    const ushort_t* asrc = oa + (size_t)(m0 + row) * CH + chk * 8;
    const ushort_t* bsrc = wob + (size_t)(c0 + row) * CH + chk * 8;
    floatx4 acc[4] = {};
    uint4 ra = *(const uint4*)(asrc);
    uint4 rb = *(const uint4*)(bsrc);
    for (int k0 = 0; k0 < 8; k0++) {
        *(uint4*)&Al[row][chk * 8] = ra;
        *(uint4*)&Bl[row][chk * 8] = rb;
        __syncthreads();
        if (k0 < 7) {
            ra = *(const uint4*)(asrc + (k0 + 1) * 32);
            rb = *(const uint4*)(bsrc + (k0 + 1) * 32);
        }
        s16x8 af = *(const s16x8*)&Al[wave * 16 + lr][lk * 8];
        #pragma unroll
        for (int ct = 0; ct < 4; ct++) {
            s16x8 bf = *(const s16x8*)&Bl[ct * 16 + lr][lk * 8];
            acc[ct] = __builtin_amdgcn_mfma_f32_16x16x32_bf16(af, bf, acc[ct], 0, 0, 0);
        }
        __syncthreads();
    }
    int mrow0 = m0 + wave * 16 + (lk << 2);
    int b = mrow0 >> 12;
    int n = mrow0 & 4095;
    #pragma unroll
    for (int ct = 0; ct < 4; ct++) {
        int c = c0 + ct * 16 + lr;
        const float4 xv = *(const float4*)(x + ((size_t)(b * CH + c)) * HW + n);
        float4 ov;
        ov.x = acc[ct][0] + xv.x;
        ov.y = acc[ct][1] + xv.y;
        ov.z = acc[ct][2] + xv.z;
        ov.w = acc[ct][3] + xv.w;
        *(float4*)(out + ((size_t)(b * CH + c)) * HW + n) = ov;
    }
}

extern "C" void kernel_launch(void* const* d_in, const int* in_sizes, int n_in,
                              void* d_out, int out_size, void* d_ws, size_t ws_size,
                              hipStream_t stream) {
    const float* x    = (const float*)d_in[0];
    const float* gw   = (const float*)d_in[1];
    const float* gb   = (const float*)d_in[2];
    const float* wqkv = (const float*)d_in[3];
    const float* wout = (const float*)d_in[4];
    float* out = (float*)d_out;

    char* ws = (char*)d_ws;
    float* stats = (float*)ws;
    ushort_t* xn = (ushort_t*)(ws + 512);
    size_t per = (size_t)BATCH * HW * CH;
    ushort_t* q   = xn + per;
    ushort_t* k   = q + per;
    ushort_t* v   = k + per;
    ushort_t* oa  = v + per;
    ushort_t* wqb = oa + per;            // 196608 elements
    ushort_t* wob = wqb + 196608;        // 65536 elements

    gn_stats_wcvt<<<320, 256, 0, stream>>>(x, stats, wqkv, wout, wqb);
    norm_transpose<<<dim3(64, 8, 2), 256, 0, stream>>>(x, stats, gw, gb, xn);
    qkv_gemm<<<dim3(64, 12, 2), 256, 0, stream>>>(xn, wqb, q, k, v);
    attn8<<<dim3(64, 16), 256, 0, stream>>>(q, k, v, oa);
    proj_res<<<dim3(128, 4), 256, 0, stream>>>(oa, wob, x, out);
}